// Round 9
// baseline (397.717 us; speedup 1.0000x reference)
//
#include <hip/hip_runtime.h>
#include <stdint.h>

// Problem constants
#define BB 4
#define TT 2048
#define CC 1024
#define HH 16
#define DH 64
#define NQKV 3072

typedef __bf16 bf16_t;
typedef __attribute__((ext_vector_type(8))) __bf16 bf16x8;
typedef __attribute__((ext_vector_type(4))) float f32x4;

#define MFMA16(a, b, c) __builtin_amdgcn_mfma_f32_16x16x32_bf16((a), (b), (c), 0, 0, 0)

// async global->LDS, 16B per lane. LDS dest = wave-uniform base + lane*16.
__device__ __forceinline__ void gll16(const void* g, void* l) {
  typedef const __attribute__((address_space(1))) void* gp_t;
  typedef __attribute__((address_space(3))) void* lp_t;
  __builtin_amdgcn_global_load_lds((gp_t)(uintptr_t)g, (lp_t)(uintptr_t)l, 16, 0, 0);
}

// ---------------------------------------------------------------------------
// fp32 -> bf16 convert, 8 elems/thread (n multiple of 2048)
// ---------------------------------------------------------------------------
__global__ __launch_bounds__(256) void cvt_k(const float* __restrict__ src,
                                             bf16_t* __restrict__ dst, int n) {
  const int i8 = (blockIdx.x * 256 + threadIdx.x) * 8;
  if (i8 < n) {
    const f32x4 a = *(const f32x4*)(src + i8);
    const f32x4 b = *(const f32x4*)(src + i8 + 4);
    bf16x8 r;
    r[0] = (bf16_t)a[0]; r[1] = (bf16_t)a[1]; r[2] = (bf16_t)a[2]; r[3] = (bf16_t)a[3];
    r[4] = (bf16_t)b[0]; r[5] = (bf16_t)b[1]; r[6] = (bf16_t)b[2]; r[7] = (bf16_t)b[3];
    *(bf16x8*)(dst + i8) = r;
  }
}

// ---------------------------------------------------------------------------
// GEMM (bf16 A, bf16 W): C[m][n] = sum_k A[m][k]*W[n][k] (+bias[n]); K=1024.
// BK=64 as two BK=32 half-tiles. LDS is XOR-swizzled: logical (row r, chunk cc)
// lives at slot r*4 + (cc ^ (r&3)). gll16's DMA lands lane l at slot l, so the
// GATHER is permuted (lane l fetches the global chunk destined for its slot).
// Fragment reads go through the same swizzle -> 2-way banked (free) instead of
// the linear layout's 4-way (6.3e6 SQ_LDS_BANK_CONFLICT in R8).
// EPI==0: qkv epilogue (RoPE Q/K, 0.125*log2e folded into Q, scatter B,H,T,dh)
// EPI==1: bias epilogue into fp32 out0
// ---------------------------------------------------------------------------
template <int EPI>
__global__ __launch_bounds__(256) void gemm_k(
    const bf16_t* __restrict__ A, const bf16_t* __restrict__ W,
    const float* __restrict__ bias,
    const float* __restrict__ fcos, const float* __restrict__ fsin,
    void* __restrict__ out0v, bf16_t* __restrict__ out1,
    bf16_t* __restrict__ out2) {
  __shared__ bf16_t Alds[2][128 * 32];
  __shared__ bf16_t Blds[2][128 * 32];
  const int K = 1024;
  const int tid = threadIdx.x;
  const int lane = tid & 63, wave = tid >> 6;
  const int quad = lane >> 4, c = lane & 15;
  const int wm = wave >> 1, wn = wave & 1;
  const int mbase = blockIdx.y * 128, nbase = blockIdx.x * 128;

  f32x4 acc[4][4];
#pragma unroll
  for (int i = 0; i < 4; ++i)
#pragma unroll
    for (int j = 0; j < 4; ++j) acc[i][j] = (f32x4){0.f, 0.f, 0.f, 0.f};

  // permuted gather: slot s=tid (+256) holds logical (r=s>>2, cc=(s&3)^(r&3))
  const int s0 = tid, s1 = tid + 256;
  const int r0 = s0 >> 2, cc0 = (s0 & 3) ^ (r0 & 3);
  const int r1 = s1 >> 2, cc1 = (s1 & 3) ^ (r1 & 3);
  const bf16_t* ag0 = A + (mbase + r0) * K + cc0 * 8;
  const bf16_t* ag1 = A + (mbase + r1) * K + cc1 * 8;
  const bf16_t* bg0 = W + (nbase + r0) * K + cc0 * 8;
  const bf16_t* bg1 = W + (nbase + r1) * K + cc1 * 8;

  for (int k0 = 0; k0 < K; k0 += 64) {
    __syncthreads();  // previous tile's readers done
    gll16(ag0 + k0, &Alds[0][s0 * 8]);
    gll16(ag1 + k0, &Alds[0][s1 * 8]);
    gll16(bg0 + k0, &Blds[0][s0 * 8]);
    gll16(bg1 + k0, &Blds[0][s1 * 8]);
    gll16(ag0 + k0 + 32, &Alds[1][s0 * 8]);
    gll16(ag1 + k0 + 32, &Alds[1][s1 * 8]);
    gll16(bg0 + k0 + 32, &Blds[1][s0 * 8]);
    gll16(bg1 + k0 + 32, &Blds[1][s1 * 8]);
    __syncthreads();  // DMA drained
#pragma unroll
    for (int half = 0; half < 2; ++half) {
      bf16x8 af[4], bfr[4];
#pragma unroll
      for (int mi = 0; mi < 4; ++mi) {
        const int row = wm * 64 + mi * 16 + c;
        af[mi] = *(const bf16x8*)&Alds[half][(row * 4 + (quad ^ (row & 3))) * 8];
      }
#pragma unroll
      for (int ni = 0; ni < 4; ++ni) {
        const int row = wn * 64 + ni * 16 + c;
        bfr[ni] = *(const bf16x8*)&Blds[half][(row * 4 + (quad ^ (row & 3))) * 8];
      }
#pragma unroll
      for (int mi = 0; mi < 4; ++mi)
#pragma unroll
        for (int ni = 0; ni < 4; ++ni)
          acc[mi][ni] = MFMA16(af[mi], bfr[ni], acc[mi][ni]);
    }
  }

  // epilogue. C/D layout: col = lane&15 (+16*ni), row = quad*4 + r (+16*mi)
  const float qscale = 0.18033688011112042f;  // 0.125 * log2(e)
#pragma unroll
  for (int mi = 0; mi < 4; ++mi) {
#pragma unroll
    for (int ni = 0; ni < 4; ++ni) {
      const int n = nbase + wn * 64 + ni * 16 + c;
      const float bv = bias[n];
#pragma unroll
      for (int r = 0; r < 4; ++r) {
        const int m = mbase + wm * 64 + mi * 16 + quad * 4 + r;
        float v = acc[mi][ni][r] + bv;
        if (EPI == 0) {
          bf16_t* out0 = (bf16_t*)out0v;
          const int sel = n >> 10;  // 0=q 1=k 2=v
          const int nl = n & 1023;
          const int h = nl >> 6, d = nl & 63;
          const int b = m >> 11, t = m & 2047;
          const int dst = ((b * HH + h) * TT + t) * DH + d;
          if (sel < 2) {
            const float pv = __shfl_xor(v, 1, 64);  // RoPE partner (col n^1)
            const int d2 = d >> 1;
            const float cs = fcos[t * 32 + d2];
            const float sn = fsin[t * 32 + d2];
            float o = ((d & 1) == 0) ? (v * cs - pv * sn) : (pv * sn + v * cs);
            if (sel == 0) {
              o *= qscale;
              out0[dst] = (bf16_t)o;
            } else {
              out1[dst] = (bf16_t)o;
            }
          } else {
            out2[dst] = (bf16_t)v;
          }
        } else {
          float* outf = (float*)out0v;
          outf[m * CC + n] = v;
        }
      }
    }
  }
}

// ---------------------------------------------------------------------------
// Flash attention, causal. Q pre-scaled by 0.125*log2(e) (exp2 domain).
// Uniform-work causal pairing (R7): exactly 33 kv-iterations per block.
// R9: K fragments read DIRECTLY from global (coalesced key*64+quad*8 pattern,
// 8KB tile L1/L2-resident, shared by 4 waves) -- K LDS tile and its staging
// removed, cutting block LDS-read traffic ~33%. V stays LDS-transposed
// (dbuf), P per-wave LDS. Swizzles byte-identical to R5/R8 (0 conflicts).
// ---------------------------------------------------------------------------
__global__ __launch_bounds__(256, 4) void attn_k(const bf16_t* __restrict__ Q,
                                                 const bf16_t* __restrict__ Kv,
                                                 const bf16_t* __restrict__ V,
                                                 bf16_t* __restrict__ O) {
  __shared__ bf16_t VtS[2][64 * 64];  // 16 KB, row=d, chunks=key
  __shared__ bf16_t PS[4][16 * 64];   // per-wave P, 8 KB

  const int tid = threadIdx.x;
  const int lane = tid & 63, wave = tid >> 6;
  const int quad = lane >> 4, c = lane & 15;
  const int bi = blockIdx.x;
  const int pair = bi & 15, h = (bi >> 4) & 15, b = bi >> 8;
  const int qtA = pair, qtB = 31 - pair;
  const int nA = qtA + 1;  // kv tiles in phase A

  const bf16_t* Qh = Q + ((b * HH + h) * TT) * DH;
  const bf16_t* Kh = Kv + ((b * HH + h) * TT) * DH;
  const bf16_t* Vh = V + ((b * HH + h) * TT) * DH;

  const f32x4 zero4 = {0.f, 0.f, 0.f, 0.f};
  bf16x8 ones8;
#pragma unroll
  for (int i = 0; i < 8; ++i) ones8[i] = (bf16_t)1.0f;

  // V staging (per-thread, loop-invariant)
  const int vsb = tid >> 2, vjp = tid & 3;
  const int vrg = vsb & 7, vc8 = vsb >> 3;
  const int vd0 = vc8 * 8 + vjp * 2, vd1 = vd0 + 1;
  const bf16_t* vbase = Vh + vrg * 8 * DH + vd0;

  // invariant swizzled fragment offsets (elements)
  const int sw = c & 7;
  const int e0 = c * 64 + (quad ^ sw) * 8;
  const int e1 = c * 64 + ((quad + 4) ^ sw) * 8;
  // invariant K global lane offset: key-in-tile = c, k-dims quad*8
  const int koff = c * DH + quad * 8;

  uint32_t vr[8];
  auto load_tile = [&](int eoff) {
    const bf16_t* vp = vbase + eoff;
#pragma unroll
    for (int i = 0; i < 8; ++i) vr[i] = *(const uint32_t*)(vp + i * DH);
  };
  auto store_tile = [&](int buf) {
    union { bf16x8 v; uint16_t u[8]; } colA, colB;
#pragma unroll
    for (int i = 0; i < 8; ++i) {
      colA.u[i] = (uint16_t)(vr[i] & 0xffffu);
      colB.u[i] = (uint16_t)(vr[i] >> 16);
    }
    *(bf16x8*)&VtS[buf][(vd0 * 8 + (vrg ^ (vd0 & 7))) * 8] = colA.v;
    *(bf16x8*)&VtS[buf][(vd1 * 8 + (vrg ^ (vd1 & 7))) * 8] = colB.v;
  };

  // phase state (A first)
  int qtbase = qtA * 64;
  bf16x8 qf0 = *(const bf16x8*)(Qh + (qtbase + wave * 16 + c) * DH + quad * 8);
  bf16x8 qf1 = *(const bf16x8*)(Qh + (qtbase + wave * 16 + c) * DH + 32 + quad * 8);

  f32x4 o_acc[4] = {zero4, zero4, zero4, zero4};
  float m_r[4] = {-1e30f, -1e30f, -1e30f, -1e30f};
  float l_r[4] = {0.f, 0.f, 0.f, 0.f};

  auto write_O = [&](int qtb) {
#pragma unroll
    for (int r = 0; r < 4; ++r) {
      const int qg = qtb + wave * 16 + quad * 4 + r;
      const float inv = 1.0f / l_r[r];
#pragma unroll
      for (int ni = 0; ni < 4; ++ni)
        O[(b * TT + qg) * CC + h * 64 + ni * 16 + c] =
            (bf16_t)(o_acc[ni][r] * inv);
    }
  };

  load_tile(0);
  store_tile(0);
  __syncthreads();
  int coff = 0;   // current tile element offset into V
  int kkey = 0;   // current tile key-index base

// one kv iteration; CUR is a literal 0/1 -> LDS addresses fold to constants
#define ATTN_ITER(FI, CUR)                                                     \
  {                                                                            \
    const int fi_ = (FI);                                                      \
    const bool pre_ = fi_ < 32;                                                \
    const int noff_ = (fi_ + 1 == nA) ? 0 : coff + 64 * DH;                    \
    if (pre_) load_tile(noff_);                                                \
    const bf16_t* kt_ = Kh + kkey * DH + koff;                                 \
    bf16x8 kf0[4], kf1[4];                                                     \
    _Pragma("unroll") for (int ni = 0; ni < 4; ++ni) {                         \
      kf0[ni] = *(const bf16x8*)(kt_ + ni * 16 * DH);                          \
      kf1[ni] = *(const bf16x8*)(kt_ + ni * 16 * DH + 32);                     \
    }                                                                          \
    f32x4 s[4];                                                                \
    _Pragma("unroll") for (int ni = 0; ni < 4; ++ni) {                         \
      f32x4 t = MFMA16(qf0, kf0[ni], zero4);                                   \
      t = MFMA16(qf1, kf1[ni], t);                                             \
      s[ni] = t;                                                               \
    }                                                                          \
    const int minq_ = qtbase + wave * 16;                                      \
    if (kkey + 63 > minq_) {                                                   \
      _Pragma("unroll") for (int ni = 0; ni < 4; ++ni)                         \
          _Pragma("unroll") for (int r = 0; r < 4; ++r) {                      \
        const int key_ = kkey + ni * 16 + c;                                   \
        const int qg_ = minq_ + quad * 4 + r;                                  \
        if (key_ > qg_) s[ni][r] = -1e30f;                                     \
      }                                                                        \
    }                                                                          \
    float alpha[4];                                                            \
    _Pragma("unroll") for (int r = 0; r < 4; ++r) {                            \
      float mx = fmaxf(fmaxf(s[0][r], s[1][r]), fmaxf(s[2][r], s[3][r]));      \
      mx = fmaxf(mx, __shfl_xor(mx, 1, 64));                                   \
      mx = fmaxf(mx, __shfl_xor(mx, 2, 64));                                   \
      mx = fmaxf(mx, __shfl_xor(mx, 4, 64));                                   \
      mx = fmaxf(mx, __shfl_xor(mx, 8, 64));                                   \
      const float mnew = fmaxf(m_r[r], mx);                                    \
      alpha[r] = __builtin_amdgcn_exp2f(m_r[r] - mnew);                        \
      m_r[r] = mnew;                                                           \
    }                                                                          \
    _Pragma("unroll") for (int ni = 0; ni < 4; ++ni)                           \
        _Pragma("unroll") for (int r = 0; r < 4; ++r) {                        \
      const float p = __builtin_amdgcn_exp2f(s[ni][r] - m_r[r]);               \
      const int prow_ = quad * 4 + r, pcol_ = ni * 16 + c;                     \
      PS[wave][(prow_ * 8 + ((pcol_ >> 3) ^ (prow_ & 7))) * 8 + (pcol_ & 7)] = \
          (bf16_t)p;                                                           \
    }                                                                          \
    _Pragma("unroll") for (int r = 0; r < 4; ++r) {                            \
      _Pragma("unroll") for (int ni = 0; ni < 4; ++ni)                         \
          o_acc[ni][r] *= alpha[r];                                            \
    }                                                                          \
    asm volatile("s_waitcnt lgkmcnt(0)" ::: "memory");                         \
    const bf16x8 p0 = *(const bf16x8*)&PS[wave][e0];                           \
    const bf16x8 p1 = *(const bf16x8*)&PS[wave][e1];                           \
    f32x4 rs = MFMA16(p0, ones8, zero4);                                       \
    rs = MFMA16(p1, ones8, rs);                                                \
    _Pragma("unroll") for (int ni = 0; ni < 4; ++ni) {                         \
      const bf16x8 v0 = *(const bf16x8*)&VtS[CUR][ni * 1024 + e0];             \
      const bf16x8 v1 = *(const bf16x8*)&VtS[CUR][ni * 1024 + e1];             \
      o_acc[ni] = MFMA16(p0, v0, o_acc[ni]);                                   \
      o_acc[ni] = MFMA16(p1, v1, o_acc[ni]);                                   \
    }                                                                          \
    _Pragma("unroll") for (int r = 0; r < 4; ++r)                              \
        l_r[r] = l_r[r] * alpha[r] + rs[r];                                    \
    if (fi_ == nA - 1) {                                                       \
      write_O(qtbase);                                                         \
      qtbase = qtB * 64;                                                       \
      qf0 = *(const bf16x8*)(Qh + (qtbase + wave * 16 + c) * DH + quad * 8);   \
      qf1 = *(const bf16x8*)(Qh + (qtbase + wave * 16 + c) * DH + 32 +         \
                             quad * 8);                                        \
      _Pragma("unroll") for (int r = 0; r < 4; ++r) {                          \
        m_r[r] = -1e30f;                                                       \
        l_r[r] = 0.f;                                                          \
      }                                                                        \
      _Pragma("unroll") for (int ni = 0; ni < 4; ++ni) o_acc[ni] = zero4;      \
    }                                                                          \
    if (pre_) store_tile(1 - (CUR));                                           \
    __syncthreads();                                                           \
    coff = noff_;                                                              \
    kkey = (fi_ + 1 == nA) ? 0 : kkey + 64;                                    \
  }

  for (int fj = 0; fj < 16; ++fj) {
    ATTN_ITER(2 * fj, 0)
    ATTN_ITER(2 * fj + 1, 1)
  }
  ATTN_ITER(32, 0)
#undef ATTN_ITER

  write_O(qtbase);  // phase B epilogue
}

// ---------------------------------------------------------------------------
extern "C" void kernel_launch(void* const* d_in, const int* in_sizes, int n_in,
                              void* d_out, int out_size, void* d_ws,
                              size_t ws_size, hipStream_t stream) {
  // Resolve inputs by unique element-count signature.
  const float *x = nullptr, *fcos = nullptr, *fsin = nullptr;
  const float *qkv_w = nullptr, *qkv_b = nullptr, *proj_w = nullptr, *proj_b = nullptr;
  for (int i = 0; i < n_in; ++i) {
    const int s = in_sizes[i];
    const float* p = (const float*)d_in[i];
    if (s == BB * TT * CC) x = p;                        // 8388608
    else if (s == TT * (DH / 2)) { if (!fcos) fcos = p; else fsin = p; }
    else if (s == NQKV * CC) qkv_w = p;                  // 3145728
    else if (s == NQKV) qkv_b = p;                       // 3072
    else if (s == CC * CC) proj_w = p;                   // 1048576
    else if (s == CC) proj_b = p;                        // 1024
    // mask (TT*TT) unused; causality is structural
  }

  const size_t NE = (size_t)BB * TT * CC;  // 8388608
  bf16_t* Qb = (bf16_t*)d_ws;
  bf16_t* Kb = Qb + NE;
  bf16_t* Vb = Kb + NE;
  bf16_t* Ob = Vb + NE;
  // dead-region reuse (all hazard-free under stream ordering):
  bf16_t* xb = Ob;                 // x_bf16 lives in Ob region until attn
  bf16_t* wqkvb = (bf16_t*)d_out;  // qkv_w bf16 in d_out until gemm3 writes it
  bf16_t* wpb = Qb;                // proj_w bf16 in Qb region (dead after attn)

  // converts
  cvt_k<<<dim3((int)(NE / 2048)), 256, 0, stream>>>(x, xb, (int)NE);
  cvt_k<<<dim3(NQKV * CC / 2048), 256, 0, stream>>>(qkv_w, wqkvb, NQKV * CC);

  // 1) qkv = x @ qkv_w^T + b, fused RoPE + head-split (+0.125*log2e into Q)
  gemm_k<0><<<dim3(NQKV / 128, (BB * TT) / 128), 256, 0, stream>>>(
      xb, wqkvb, qkv_b, fcos, fsin, (void*)Qb, Kb, Vb);
  // 2) causal flash attention -> Ob (B*T, C) bf16 (overwrites xb)
  attn_k<<<dim3(BB * HH * 16), 256, 0, stream>>>(Qb, Kb, Vb, Ob);
  // 3) convert proj_w (Qb dead now), then out = Ob @ proj_w^T + proj_b (fp32)
  cvt_k<<<dim3(CC * CC / 2048), 256, 0, stream>>>(proj_w, wpb, CC * CC);
  gemm_k<1><<<dim3(CC / 128, (BB * TT) / 128), 256, 0, stream>>>(
      Ob, wpb, proj_b, nullptr, nullptr, d_out, nullptr, nullptr);
}

// Round 10
// 325.579 us; speedup vs baseline: 1.2216x; 1.2216x over previous
//
#include <hip/hip_runtime.h>
#include <stdint.h>

// Problem constants
#define BB 4
#define TT 2048
#define CC 1024
#define HH 16
#define DH 64
#define NQKV 3072

typedef __bf16 bf16_t;
typedef __attribute__((ext_vector_type(8))) __bf16 bf16x8;
typedef __attribute__((ext_vector_type(4))) float f32x4;

#define MFMA16(a, b, c) __builtin_amdgcn_mfma_f32_16x16x32_bf16((a), (b), (c), 0, 0, 0)

// async global->LDS, 16B per lane. LDS dest = wave-uniform base + lane*16.
__device__ __forceinline__ void gll16(const void* g, void* l) {
  typedef const __attribute__((address_space(1))) void* gp_t;
  typedef __attribute__((address_space(3))) void* lp_t;
  __builtin_amdgcn_global_load_lds((gp_t)(uintptr_t)g, (lp_t)(uintptr_t)l, 16, 0, 0);
}

// ---------------------------------------------------------------------------
// fp32 -> bf16 convert, 8 elems/thread (n multiple of 2048)
// ---------------------------------------------------------------------------
__global__ __launch_bounds__(256) void cvt_k(const float* __restrict__ src,
                                             bf16_t* __restrict__ dst, int n) {
  const int i8 = (blockIdx.x * 256 + threadIdx.x) * 8;
  if (i8 < n) {
    const f32x4 a = *(const f32x4*)(src + i8);
    const f32x4 b = *(const f32x4*)(src + i8 + 4);
    bf16x8 r;
    r[0] = (bf16_t)a[0]; r[1] = (bf16_t)a[1]; r[2] = (bf16_t)a[2]; r[3] = (bf16_t)a[3];
    r[4] = (bf16_t)b[0]; r[5] = (bf16_t)b[1]; r[6] = (bf16_t)b[2]; r[7] = (bf16_t)b[3];
    *(bf16x8*)(dst + i8) = r;
  }
}

// ---------------------------------------------------------------------------
// GEMM (bf16 A, bf16 W): C[m][n] = sum_k A[m][k]*W[n][k] (+bias[n]); K=1024.
// BK=64 as two BK=32 half-tiles. LDS is XOR-swizzled: logical (row r, chunk cc)
// lives at slot r*4 + (cc ^ (r&3)). gll16's DMA lands lane l at slot l, so the
// GATHER is permuted (lane l fetches the global chunk destined for its slot).
// Fragment reads go through the same swizzle -> 2-way banked (free) instead of
// the linear layout's 4-way (6.3e6 SQ_LDS_BANK_CONFLICT in R8). [R9-verified]
// EPI==0: qkv epilogue (RoPE Q/K, 0.125*log2e folded into Q, scatter B,H,T,dh)
// EPI==1: bias epilogue into fp32 out0
// ---------------------------------------------------------------------------
template <int EPI>
__global__ __launch_bounds__(256) void gemm_k(
    const bf16_t* __restrict__ A, const bf16_t* __restrict__ W,
    const float* __restrict__ bias,
    const float* __restrict__ fcos, const float* __restrict__ fsin,
    void* __restrict__ out0v, bf16_t* __restrict__ out1,
    bf16_t* __restrict__ out2) {
  __shared__ bf16_t Alds[2][128 * 32];
  __shared__ bf16_t Blds[2][128 * 32];
  const int K = 1024;
  const int tid = threadIdx.x;
  const int lane = tid & 63, wave = tid >> 6;
  const int quad = lane >> 4, c = lane & 15;
  const int wm = wave >> 1, wn = wave & 1;
  const int mbase = blockIdx.y * 128, nbase = blockIdx.x * 128;

  f32x4 acc[4][4];
#pragma unroll
  for (int i = 0; i < 4; ++i)
#pragma unroll
    for (int j = 0; j < 4; ++j) acc[i][j] = (f32x4){0.f, 0.f, 0.f, 0.f};

  // permuted gather: slot s=tid (+256) holds logical (r=s>>2, cc=(s&3)^(r&3))
  const int s0 = tid, s1 = tid + 256;
  const int r0 = s0 >> 2, cc0 = (s0 & 3) ^ (r0 & 3);
  const int r1 = s1 >> 2, cc1 = (s1 & 3) ^ (r1 & 3);
  const bf16_t* ag0 = A + (mbase + r0) * K + cc0 * 8;
  const bf16_t* ag1 = A + (mbase + r1) * K + cc1 * 8;
  const bf16_t* bg0 = W + (nbase + r0) * K + cc0 * 8;
  const bf16_t* bg1 = W + (nbase + r1) * K + cc1 * 8;

  for (int k0 = 0; k0 < K; k0 += 64) {
    __syncthreads();  // previous tile's readers done
    gll16(ag0 + k0, &Alds[0][s0 * 8]);
    gll16(ag1 + k0, &Alds[0][s1 * 8]);
    gll16(bg0 + k0, &Blds[0][s0 * 8]);
    gll16(bg1 + k0, &Blds[0][s1 * 8]);
    gll16(ag0 + k0 + 32, &Alds[1][s0 * 8]);
    gll16(ag1 + k0 + 32, &Alds[1][s1 * 8]);
    gll16(bg0 + k0 + 32, &Blds[1][s0 * 8]);
    gll16(bg1 + k0 + 32, &Blds[1][s1 * 8]);
    __syncthreads();  // DMA drained
#pragma unroll
    for (int half = 0; half < 2; ++half) {
      bf16x8 af[4], bfr[4];
#pragma unroll
      for (int mi = 0; mi < 4; ++mi) {
        const int row = wm * 64 + mi * 16 + c;
        af[mi] = *(const bf16x8*)&Alds[half][(row * 4 + (quad ^ (row & 3))) * 8];
      }
#pragma unroll
      for (int ni = 0; ni < 4; ++ni) {
        const int row = wn * 64 + ni * 16 + c;
        bfr[ni] = *(const bf16x8*)&Blds[half][(row * 4 + (quad ^ (row & 3))) * 8];
      }
#pragma unroll
      for (int mi = 0; mi < 4; ++mi)
#pragma unroll
        for (int ni = 0; ni < 4; ++ni)
          acc[mi][ni] = MFMA16(af[mi], bfr[ni], acc[mi][ni]);
    }
  }

  // epilogue. C/D layout: col = lane&15 (+16*ni), row = quad*4 + r (+16*mi)
  const float qscale = 0.18033688011112042f;  // 0.125 * log2(e)
#pragma unroll
  for (int mi = 0; mi < 4; ++mi) {
#pragma unroll
    for (int ni = 0; ni < 4; ++ni) {
      const int n = nbase + wn * 64 + ni * 16 + c;
      const float bv = bias[n];
#pragma unroll
      for (int r = 0; r < 4; ++r) {
        const int m = mbase + wm * 64 + mi * 16 + quad * 4 + r;
        float v = acc[mi][ni][r] + bv;
        if (EPI == 0) {
          bf16_t* out0 = (bf16_t*)out0v;
          const int sel = n >> 10;  // 0=q 1=k 2=v
          const int nl = n & 1023;
          const int h = nl >> 6, d = nl & 63;
          const int b = m >> 11, t = m & 2047;
          const int dst = ((b * HH + h) * TT + t) * DH + d;
          if (sel < 2) {
            const float pv = __shfl_xor(v, 1, 64);  // RoPE partner (col n^1)
            const int d2 = d >> 1;
            const float cs = fcos[t * 32 + d2];
            const float sn = fsin[t * 32 + d2];
            float o = ((d & 1) == 0) ? (v * cs - pv * sn) : (pv * sn + v * cs);
            if (sel == 0) {
              o *= qscale;
              out0[dst] = (bf16_t)o;
            } else {
              out1[dst] = (bf16_t)o;
            }
          } else {
            out2[dst] = (bf16_t)v;
          }
        } else {
          float* outf = (float*)out0v;
          outf[m * CC + n] = v;
        }
      }
    }
  }
}

// ---------------------------------------------------------------------------
// Flash attention, causal. Q pre-scaled by 0.125*log2(e) (exp2 domain).
// R8-verified version (REVERT of R9's global-K experiment: MFMA operands must
// come from a buffer filled >=1 iteration ahead; direct global K reads put
// ~200-900cyc load latency on the critical path -> 105->174us regression).
// Uniform-work causal pairing: exactly 33 kv-iterations per block; kv-loop
// unrolled x2 (compile-time LDS buffer index); rowsum via MFMA vs ones;
// XOR-swizzled LDS (0 bank conflicts).
// ---------------------------------------------------------------------------
__global__ __launch_bounds__(256, 4) void attn_k(const bf16_t* __restrict__ Q,
                                                 const bf16_t* __restrict__ Kv,
                                                 const bf16_t* __restrict__ V,
                                                 bf16_t* __restrict__ O) {
  __shared__ bf16_t KS[2][64 * 64];
  __shared__ bf16_t VtS[2][64 * 64];
  __shared__ bf16_t PS[4][16 * 64];

  const int tid = threadIdx.x;
  const int lane = tid & 63, wave = tid >> 6;
  const int quad = lane >> 4, c = lane & 15;
  const int bi = blockIdx.x;
  const int pair = bi & 15, h = (bi >> 4) & 15, b = bi >> 8;
  const int qtA = pair, qtB = 31 - pair;
  const int nA = qtA + 1;  // kv tiles in phase A

  const bf16_t* Qh = Q + ((b * HH + h) * TT) * DH;
  const bf16_t* Kh = Kv + ((b * HH + h) * TT) * DH;
  const bf16_t* Vh = V + ((b * HH + h) * TT) * DH;

  const f32x4 zero4 = {0.f, 0.f, 0.f, 0.f};
  bf16x8 ones8;
#pragma unroll
  for (int i = 0; i < 8; ++i) ones8[i] = (bf16_t)1.0f;

  // staging bases (per-thread, loop-invariant)
  const int krow0 = tid >> 3, kc8 = tid & 7, krow1 = krow0 + 32;
  const bf16_t* kbase0 = Kh + krow0 * DH + kc8 * 8;
  const bf16_t* kbase1 = Kh + krow1 * DH + kc8 * 8;
  const int vsb = tid >> 2, vjp = tid & 3;
  const int vrg = vsb & 7, vc8 = vsb >> 3;
  const int vd0 = vc8 * 8 + vjp * 2, vd1 = vd0 + 1;
  const bf16_t* vbase = Vh + vrg * 8 * DH + vd0;

  // invariant swizzled fragment offsets (elements): row c, chunk (quad|quad+4)
  const int sw = c & 7;
  const int e0 = c * 64 + (quad ^ sw) * 8;
  const int e1 = c * 64 + ((quad + 4) ^ sw) * 8;

  bf16x8 kr0, kr1;
  uint32_t vr[8];
  auto load_tile = [&](int eoff) {
    kr0 = *(const bf16x8*)(kbase0 + eoff);
    kr1 = *(const bf16x8*)(kbase1 + eoff);
    const bf16_t* vp = vbase + eoff;
#pragma unroll
    for (int i = 0; i < 8; ++i) vr[i] = *(const uint32_t*)(vp + i * DH);
  };
  auto store_tile = [&](int buf) {
    *(bf16x8*)&KS[buf][(krow0 * 8 + (kc8 ^ (krow0 & 7))) * 8] = kr0;
    *(bf16x8*)&KS[buf][(krow1 * 8 + (kc8 ^ (krow1 & 7))) * 8] = kr1;
    union { bf16x8 v; uint16_t u[8]; } colA, colB;
#pragma unroll
    for (int i = 0; i < 8; ++i) {
      colA.u[i] = (uint16_t)(vr[i] & 0xffffu);
      colB.u[i] = (uint16_t)(vr[i] >> 16);
    }
    *(bf16x8*)&VtS[buf][(vd0 * 8 + (vrg ^ (vd0 & 7))) * 8] = colA.v;
    *(bf16x8*)&VtS[buf][(vd1 * 8 + (vrg ^ (vd1 & 7))) * 8] = colB.v;
  };

  // phase state (A first)
  int qtbase = qtA * 64;
  bf16x8 qf0 = *(const bf16x8*)(Qh + (qtbase + wave * 16 + c) * DH + quad * 8);
  bf16x8 qf1 = *(const bf16x8*)(Qh + (qtbase + wave * 16 + c) * DH + 32 + quad * 8);

  f32x4 o_acc[4] = {zero4, zero4, zero4, zero4};
  float m_r[4] = {-1e30f, -1e30f, -1e30f, -1e30f};
  float l_r[4] = {0.f, 0.f, 0.f, 0.f};

  auto write_O = [&](int qtb) {
#pragma unroll
    for (int r = 0; r < 4; ++r) {
      const int qg = qtb + wave * 16 + quad * 4 + r;
      const float inv = 1.0f / l_r[r];
#pragma unroll
      for (int ni = 0; ni < 4; ++ni)
        O[(b * TT + qg) * CC + h * 64 + ni * 16 + c] =
            (bf16_t)(o_acc[ni][r] * inv);
    }
  };

  load_tile(0);
  store_tile(0);
  __syncthreads();
  int coff = 0;   // current tile element offset into K/V
  int kkey = 0;   // current tile key-index base

// one kv iteration; CUR is a literal 0/1 -> LDS addresses fold to constants
#define ATTN_ITER(FI, CUR)                                                     \
  {                                                                            \
    const int fi_ = (FI);                                                      \
    const bool pre_ = fi_ < 32;                                                \
    const int noff_ = (fi_ + 1 == nA) ? 0 : coff + 64 * DH;                    \
    if (pre_) load_tile(noff_);                                                \
    bf16x8 kf0[4], kf1[4];                                                     \
    _Pragma("unroll") for (int ni = 0; ni < 4; ++ni) {                         \
      kf0[ni] = *(const bf16x8*)&KS[CUR][ni * 1024 + e0];                      \
      kf1[ni] = *(const bf16x8*)&KS[CUR][ni * 1024 + e1];                      \
    }                                                                          \
    f32x4 s[4];                                                                \
    _Pragma("unroll") for (int ni = 0; ni < 4; ++ni) {                         \
      f32x4 t = MFMA16(qf0, kf0[ni], zero4);                                   \
      t = MFMA16(qf1, kf1[ni], t);                                             \
      s[ni] = t;                                                               \
    }                                                                          \
    const int minq_ = qtbase + wave * 16;                                      \
    if (kkey + 63 > minq_) {                                                   \
      _Pragma("unroll") for (int ni = 0; ni < 4; ++ni)                         \
          _Pragma("unroll") for (int r = 0; r < 4; ++r) {                      \
        const int key_ = kkey + ni * 16 + c;                                   \
        const int qg_ = minq_ + quad * 4 + r;                                  \
        if (key_ > qg_) s[ni][r] = -1e30f;                                     \
      }                                                                        \
    }                                                                          \
    float alpha[4];                                                            \
    _Pragma("unroll") for (int r = 0; r < 4; ++r) {                            \
      float mx = fmaxf(fmaxf(s[0][r], s[1][r]), fmaxf(s[2][r], s[3][r]));      \
      mx = fmaxf(mx, __shfl_xor(mx, 1, 64));                                   \
      mx = fmaxf(mx, __shfl_xor(mx, 2, 64));                                   \
      mx = fmaxf(mx, __shfl_xor(mx, 4, 64));                                   \
      mx = fmaxf(mx, __shfl_xor(mx, 8, 64));                                   \
      const float mnew = fmaxf(m_r[r], mx);                                    \
      alpha[r] = __builtin_amdgcn_exp2f(m_r[r] - mnew);                        \
      m_r[r] = mnew;                                                           \
    }                                                                          \
    _Pragma("unroll") for (int ni = 0; ni < 4; ++ni)                           \
        _Pragma("unroll") for (int r = 0; r < 4; ++r) {                        \
      const float p = __builtin_amdgcn_exp2f(s[ni][r] - m_r[r]);               \
      const int prow_ = quad * 4 + r, pcol_ = ni * 16 + c;                     \
      PS[wave][(prow_ * 8 + ((pcol_ >> 3) ^ (prow_ & 7))) * 8 + (pcol_ & 7)] = \
          (bf16_t)p;                                                           \
    }                                                                          \
    _Pragma("unroll") for (int r = 0; r < 4; ++r) {                            \
      _Pragma("unroll") for (int ni = 0; ni < 4; ++ni)                         \
          o_acc[ni][r] *= alpha[r];                                            \
    }                                                                          \
    asm volatile("s_waitcnt lgkmcnt(0)" ::: "memory");                         \
    const bf16x8 p0 = *(const bf16x8*)&PS[wave][e0];                           \
    const bf16x8 p1 = *(const bf16x8*)&PS[wave][e1];                           \
    f32x4 rs = MFMA16(p0, ones8, zero4);                                       \
    rs = MFMA16(p1, ones8, rs);                                                \
    _Pragma("unroll") for (int ni = 0; ni < 4; ++ni) {                         \
      const bf16x8 v0 = *(const bf16x8*)&VtS[CUR][ni * 1024 + e0];             \
      const bf16x8 v1 = *(const bf16x8*)&VtS[CUR][ni * 1024 + e1];             \
      o_acc[ni] = MFMA16(p0, v0, o_acc[ni]);                                   \
      o_acc[ni] = MFMA16(p1, v1, o_acc[ni]);                                   \
    }                                                                          \
    _Pragma("unroll") for (int r = 0; r < 4; ++r)                              \
        l_r[r] = l_r[r] * alpha[r] + rs[r];                                    \
    if (fi_ == nA - 1) {                                                       \
      write_O(qtbase);                                                         \
      qtbase = qtB * 64;                                                       \
      qf0 = *(const bf16x8*)(Qh + (qtbase + wave * 16 + c) * DH + quad * 8);   \
      qf1 = *(const bf16x8*)(Qh + (qtbase + wave * 16 + c) * DH + 32 +         \
                             quad * 8);                                        \
      _Pragma("unroll") for (int r = 0; r < 4; ++r) {                          \
        m_r[r] = -1e30f;                                                       \
        l_r[r] = 0.f;                                                          \
      }                                                                        \
      _Pragma("unroll") for (int ni = 0; ni < 4; ++ni) o_acc[ni] = zero4;      \
    }                                                                          \
    if (pre_) store_tile(1 - (CUR));                                           \
    __syncthreads();                                                           \
    coff = noff_;                                                              \
    kkey = (fi_ + 1 == nA) ? 0 : kkey + 64;                                    \
  }

  for (int fj = 0; fj < 16; ++fj) {
    ATTN_ITER(2 * fj, 0)
    ATTN_ITER(2 * fj + 1, 1)
  }
  ATTN_ITER(32, 0)
#undef ATTN_ITER

  write_O(qtbase);  // phase B epilogue
}

// ---------------------------------------------------------------------------
extern "C" void kernel_launch(void* const* d_in, const int* in_sizes, int n_in,
                              void* d_out, int out_size, void* d_ws,
                              size_t ws_size, hipStream_t stream) {
  // Resolve inputs by unique element-count signature.
  const float *x = nullptr, *fcos = nullptr, *fsin = nullptr;
  const float *qkv_w = nullptr, *qkv_b = nullptr, *proj_w = nullptr, *proj_b = nullptr;
  for (int i = 0; i < n_in; ++i) {
    const int s = in_sizes[i];
    const float* p = (const float*)d_in[i];
    if (s == BB * TT * CC) x = p;                        // 8388608
    else if (s == TT * (DH / 2)) { if (!fcos) fcos = p; else fsin = p; }
    else if (s == NQKV * CC) qkv_w = p;                  // 3145728
    else if (s == NQKV) qkv_b = p;                       // 3072
    else if (s == CC * CC) proj_w = p;                   // 1048576
    else if (s == CC) proj_b = p;                        // 1024
    // mask (TT*TT) unused; causality is structural
  }

  const size_t NE = (size_t)BB * TT * CC;  // 8388608
  bf16_t* Qb = (bf16_t*)d_ws;
  bf16_t* Kb = Qb + NE;
  bf16_t* Vb = Kb + NE;
  bf16_t* Ob = Vb + NE;
  // dead-region reuse (all hazard-free under stream ordering):
  bf16_t* xb = Ob;                 // x_bf16 lives in Ob region until attn
  bf16_t* wqkvb = (bf16_t*)d_out;  // qkv_w bf16 in d_out until gemm3 writes it
  bf16_t* wpb = Qb;                // proj_w bf16 in Qb region (dead after attn)

  // converts
  cvt_k<<<dim3((int)(NE / 2048)), 256, 0, stream>>>(x, xb, (int)NE);
  cvt_k<<<dim3(NQKV * CC / 2048), 256, 0, stream>>>(qkv_w, wqkvb, NQKV * CC);

  // 1) qkv = x @ qkv_w^T + b, fused RoPE + head-split (+0.125*log2e into Q)
  gemm_k<0><<<dim3(NQKV / 128, (BB * TT) / 128), 256, 0, stream>>>(
      xb, wqkvb, qkv_b, fcos, fsin, (void*)Qb, Kb, Vb);
  // 2) causal flash attention -> Ob (B*T, C) bf16 (overwrites xb)
  attn_k<<<dim3(BB * HH * 16), 256, 0, stream>>>(Qb, Kb, Vb, Ob);
  // 3) convert proj_w (Qb dead now), then out = Ob @ proj_w^T + proj_b (fp32)
  cvt_k<<<dim3(CC * CC / 2048), 256, 0, stream>>>(proj_w, wpb, CC * CC);
  gemm_k<1><<<dim3(CC / 128, (BB * TT) / 128), 256, 0, stream>>>(
      Ob, wpb, proj_b, nullptr, nullptr, d_out, nullptr, nullptr);
}